// Round 9
// baseline (214.766 us; speedup 1.0000x reference)
//
#include <hip/hip_runtime.h>
#include <hip/hip_cooperative_groups.h>
#include <math.h>

namespace cg = cooperative_groups;

// Problem dims (fixed by setup_inputs)
#define N_  8
#define C_  4
#define A_  180
#define R_  180
#define NC  (N_*C_)        // 32
#define AR  (A_*R_)        // 32400
#define CAP 1024           // max peaks per (n,c) — expected ~560
#define ROWS_PB 8          // rows per raster stripe-block
#define SL  32             // peak slices per row
#define CH  1013           // ceil(AR/32): phase-2 chunk per block

typedef unsigned long long u64;
typedef unsigned int u32;

// ws layout (bytes) — nothing host-initialized; cnt zeroed in phase 1
#define OFF_PMAX 0                       // float pmax[32*32] (4096 B) plain-stored
#define OFF_CNT  4096                    // u32 cnt[32*32] (4096 B, 128-B line per nc)
#define OFF_TBL  8192                    // float ct[180] st[180] rp[180] (2160 B)
#define OFF_PD   10368                   // float4 pdata[32][CAP] (512 KB), 16B-aligned

// exact reference predicate value at u (u-space; ct2 = |ct|):
// for ct>0, u=x; for ct<0, u=255-x. Bit-exact vs reference since f32 RN is
// negation-symmetric and (x-127.5), (127.5-x) are exact halves.
__device__ __forceinline__ float probe_d(int u, float ct2, float yst, float rp) {
  return __fsub_rn(__fadd_rn(__fmul_rn(__fsub_rn((float)u, 127.5f), ct2), yst), rp);
}

// ---------------------------------------------------------------------------
// ONE cooperative kernel, grid (32 slices, 32 nc) x 256 threads, 3 phases:
//  P1: per-block partial max (1 float4/thread) -> pmax[nc][s]; block (0,nc)
//      zeroes cnt[nc]; block (1,0) builds trig/rho tables (double cos/sin
//      rounded to f32 = XLA's correctly-rounded f32; r_phys mul-rounded).
//  P2: peaks: val > 0.5*max AND no strictly-greater 3x3 neighbor (maxpool
//      SAME, -inf pad). Branchless parallel 8-neighbor loads (clamped addr +
//      validity mask) — no serial dependent-load chain. Wave-aggregated
//      append (one atomicAdd per wave, one 128-B line per nc).
//  P3: raster (verified R6/R8 logic): d(u) monotone in u -> covered set is
//      [u1,u2); division-guided edges (one exact probe each) for ct2>=1e-3,
//      eps <= 8.4e-5/ct2 + 2e-4 < 0.09 << 0.5; else 9-probe lower_bound
//      (s starts at 256 so the empty answer u=256 is reachable — R3 lesson).
//      Per-row OR across 32 slices via shfl_xor tree, float4 tile writeout.
// Grid syncs replace ~4 dispatch boundaries (~25 us of fixed overhead).
// ---------------------------------------------------------------------------
__global__ __launch_bounds__(256) void fused_kernel(
    const float* __restrict__ hm, const float* __restrict__ mwp,
    const int* __restrict__ Hp, const int* __restrict__ Wp,
    float* __restrict__ pmax, u32* __restrict__ cnt,
    float* __restrict__ tbl, float4* __restrict__ pdata,
    float* __restrict__ out) {
  cg::grid_group grid = cg::this_grid();
  int s   = blockIdx.x;                    // slice / row-stripe 0..31
  int nc  = blockIdx.y;                    // 0..31
  int tid = threadIdx.x;
  const float* base = hm + (size_t)nc * AR;

  __shared__ float smax[4];
  __shared__ u64 rowbits[ROWS_PB][4];

  // ---------------- phase 1: partial max + cnt zero + tables ----------------
  {
    const float4* p4 = (const float4*)base;      // 8100 float4 per plane
    int i = s * 256 + tid;                       // one float4 per thread
    float m = -INFINITY;
    if (i < AR / 4) {
      float4 v = p4[i];
      m = fmaxf(fmaxf(v.x, v.y), fmaxf(v.z, v.w));
    }
    for (int off = 32; off; off >>= 1) m = fmaxf(m, __shfl_down(m, off, 64));
    if ((tid & 63) == 0) smax[tid >> 6] = m;
    __syncthreads();
    if (tid == 0) {
      pmax[nc * 32 + s] = fmaxf(fmaxf(smax[0], smax[1]), fmaxf(smax[2], smax[3]));
      if (s == 0) cnt[nc * 32] = 0u;             // plain store, pre-sync
    }
    if (s == 1 && nc == 0) {
      int H = Hp[0], W = Wp[0];
      double max_rho = sqrt((double)(W/2)*(double)(W/2) + (double)(H/2)*(double)(H/2));
      float drho = (float)(2.0 * max_rho / (double)(R_ - 1));
      if (tid < A_) {
        // theta = f32(a) * f32(pi/A) — matches jnp.arange(A,f32)*(np.pi/A)
        float theta = __fmul_rn((float)tid, (float)(3.14159265358979323846 / (double)A_));
        tbl[tid]        = (float)cos((double)theta);   // correctly-rounded f32
        tbl[A_ + tid]   = (float)sin((double)theta);
        // r_phys = (f32(r) - 89.5) * f32(delta_rho)
        tbl[2*A_ + tid] = __fmul_rn(__fsub_rn((float)tid, (float)((R_-1)*0.5)), drho);
      }
    }
  }
  grid.sync();

  // ---------------- phase 2: peak detect + compact append -------------------
  {
    float m32 = -INFINITY;
    #pragma unroll
    for (int k = 0; k < 32; ++k) m32 = fmaxf(m32, pmax[nc * 32 + k]);
    float thr = 0.5f * m32;
    int start = s * CH;
    int end   = start + CH; if (end > AR) end = AR;
    for (int idx = start + tid; idx < end; idx += 256) {
      float val = base[idx];
      bool peak = false;
      int a = 0, r = 0;
      if (val > thr) {                           // ~2% of threads
        a = idx / R_; r = idx - a * R_;
        float mx = -INFINITY;                    // max of VALID neighbors
        #pragma unroll
        for (int da = -1; da <= 1; ++da) {
          #pragma unroll
          for (int dr = -1; dr <= 1; ++dr) {
            if (da == 0 && dr == 0) continue;
            int aa = a + da, rr = r + dr;
            bool ok = (aa >= 0) && (aa < A_) && (rr >= 0) && (rr < R_);
            float nb = base[ok ? (aa * R_ + rr) : idx];  // clamped-safe load
            mx = ok ? fmaxf(mx, nb) : mx;        // 8 independent loads (MLP)
          }
        }
        peak = !(mx > val);                      // == (hm == maxpool3x3)
      }
      u64 mb = __ballot(peak);
      if (mb) {
        int lane = tid & 63;
        int leader = (int)__ffsll((long long)mb) - 1;
        u32 bslot = 0;
        if (lane == leader) bslot = atomicAdd(&cnt[nc * 32], (u32)__popcll(mb));
        bslot = (u32)__shfl((int)bslot, leader, 64);
        if (peak) {
          u32 slot = bslot + (u32)__popcll(mb & ((1ull << lane) - 1ull));
          if (slot < CAP)
            pdata[(size_t)nc * CAP + slot] =
                make_float4(tbl[a], tbl[A_ + a], tbl[2 * A_ + r], 0.0f);
        }
      }
    }
  }
  grid.sync();

  // ---------------- phase 3: raster + writeout ------------------------------
  {
    int pc = (int)cnt[nc * 32]; if (pc > CAP) pc = CAP;
    const float4* pdg = pdata + (size_t)nc * CAP;
    float mw  = mwp[0];
    float nmw = -mw;
    int row = tid >> 5;                          // 0..7
    int sub = tid & (SL - 1);                    // 0..31
    int y   = s * ROWS_PB + row;
    float ycv = __fsub_rn((float)y, 127.5f);

    u64 pm[4] = {0ull, 0ull, 0ull, 0ull};

    for (int i = sub; i < pc; i += SL) {         // contiguous 512B per wave-iter
      float4 pd = pdg[i];
      float ct = pd.x, st = pd.y, rp = pd.z;
      float ct2 = fabsf(ct);
      float yst = __fmul_rn(ycv, st);
      int u1, u2;
      if (ct2 >= 1e-3f) {
        // approx edges (rounding-free math ok; exactness comes from probes)
        float t   = rp - yst;
        float inv = __builtin_amdgcn_rcpf(ct2);  // 1-ulp v_rcp_f32
        float q1  = __fmaf_rn(t - mw, inv, 127.5f);
        float q2  = __fmaf_rn(t + mw, inv, 127.5f);
        q1 = fminf(fmaxf(q1, -2.0f), 260.0f);
        q2 = fminf(fmaxf(q2, -2.0f), 260.0f);
        int k1 = (int)ceilf(q1 - 0.5f); k1 = k1 < 0 ? 0 : (k1 > 255 ? 255 : k1);
        int k2 = (int)ceilf(q2 - 0.5f); k2 = k2 < 0 ? 0 : (k2 > 255 ? 255 : k2);
        float d1 = probe_d(k1, ct2, yst, rp);
        float d2 = probe_d(k2, ct2, yst, rp);
        u1 = k1 + ((d1 > nmw) ? 0 : 1);
        u2 = k2 + ((d2 >= mw) ? 0 : 1);
      } else {
        u1 = 0; u2 = 0;
        #pragma unroll
        for (int st2 = 256; st2; st2 >>= 1) {
          if (u1 + st2 <= 256) {
            float d = probe_d(u1 + st2 - 1, ct2, yst, rp);
            if (!(d > nmw)) u1 += st2;
          }
          if (u2 + st2 <= 256) {
            float d = probe_d(u2 + st2 - 1, ct2, yst, rp);
            if (!(d >= mw)) u2 += st2;
          }
        }
      }
      if (u1 < u2) {                             // covered u in [u1,u2)
        bool neg = ct < 0.0f;                    // map back to x-space
        int xlo = neg ? 256 - u2 : u1;
        int xhi = neg ? 255 - u1 : u2 - 1;
        #pragma unroll
        for (int w = 0; w < 4; ++w) {            // branchless word fold
          int lo = xlo - (w << 6); lo = lo < 0 ? 0 : lo;
          int hi = xhi - (w << 6); hi = hi > 63 ? 63 : hi;
          if (lo <= hi) pm[w] |= (~0ull >> (63 - hi)) & (~0ull << lo);
        }
      }
    }

    // OR-reduce across the 32 slices of each row (xor<32 stays in-row)
    #pragma unroll
    for (int m = 1; m < 32; m <<= 1) {
      pm[0] |= __shfl_xor(pm[0], m, 64);
      pm[1] |= __shfl_xor(pm[1], m, 64);
      pm[2] |= __shfl_xor(pm[2], m, 64);
      pm[3] |= __shfl_xor(pm[3], m, 64);
    }
    if (sub < 4) {                               // static-index select
      u64 v = (sub == 0) ? pm[0] : (sub == 1) ? pm[1] : (sub == 2) ? pm[2] : pm[3];
      rowbits[row][sub] = v;                     // full overwrite — no zero-init
    }
    __syncthreads();

    // bit -> float tile writeout, float4 coalesced; each pixel written once
    float* otile = out + (size_t)nc * 65536 + (size_t)s * ROWS_PB * 256;
    for (int j = tid; j < ROWS_PB * 64; j += 256) {   // 64 float4 per row
      int rr = j >> 6, c4 = j & 63;
      u64 wb = rowbits[rr][c4 >> 4];
      int sh = (c4 & 15) * 4;
      float4 v;
      v.x = (float)((wb >> sh) & 1ull);
      v.y = (float)((wb >> (sh + 1)) & 1ull);
      v.z = (float)((wb >> (sh + 2)) & 1ull);
      v.w = (float)((wb >> (sh + 3)) & 1ull);
      ((float4*)(otile + (size_t)rr * 256))[c4] = v;
    }
  }
}

// ---------------------------------------------------------------------------
extern "C" void kernel_launch(void* const* d_in, const int* in_sizes, int n_in,
                              void* d_out, int out_size, void* d_ws, size_t ws_size,
                              hipStream_t stream) {
  const float* hm  = (const float*)d_in[0];   // [8,4,180,180] f32
  const float* mwp = (const float*)d_in[1];   // [1] f32
  const int*   Hp  = (const int*)d_in[2];     // [1] i32
  const int*   Wp  = (const int*)d_in[3];     // [1] i32
  float* out = (float*)d_out;                 // [8,4,256,256] f32

  char* base = (char*)d_ws;
  float*  pmax = (float*)(base + OFF_PMAX);
  u32*    cnt  = (u32*)(base + OFF_CNT);
  float*  tbl  = (float*)(base + OFF_TBL);
  float4* pdat = (float4*)(base + OFF_PD);

  void* args[] = {(void*)&hm, (void*)&mwp, (void*)&Hp, (void*)&Wp,
                  (void*)&pmax, (void*)&cnt, (void*)&tbl, (void*)&pdat,
                  (void*)&out};
  hipLaunchCooperativeKernel((void*)fused_kernel, dim3(32, NC), dim3(256),
                             args, 0, stream);
}